// Round 16
// baseline (140.258 us; speedup 1.0000x reference)
//
#include <hip/hip_runtime.h>
#include <hip/hip_bf16.h>

// Problem constants: b=8, lq=lk=2048, d=256
#define BB 8
#define LQ 2048
#define LK 2048
#define DD 256
#define OUT0_N (BB*LQ*DD)      // LN output elements; attn follows in d_out

typedef short s16x8 __attribute__((ext_vector_type(8)));
typedef float f32x4 __attribute__((ext_vector_type(4)));

#define GAS __attribute__((address_space(1)))
#define LAS __attribute__((address_space(3)))

__device__ __forceinline__ unsigned short f2b(float x){
  unsigned int u = __float_as_uint(x);
  u += 0x7fffu + ((u >> 16) & 1u);           // RNE
  return (unsigned short)(u >> 16);
}
__device__ __forceinline__ float b2f(unsigned short h){
  return __uint_as_float(((unsigned int)h) << 16);
}
__device__ __forceinline__ float ldf(const void* p, long i, int bf){
  return bf ? b2f(((const unsigned short*)p)[i]) : ((const float*)p)[i];
}
__device__ __forceinline__ s16x8 ld8(const void* p, long i, int bf){
  if (bf) return *(const s16x8*)((const unsigned short*)p + i);
  const float* f = (const float*)p + i;
  float4 a = *(const float4*)(f);
  float4 c = *(const float4*)(f + 4);
  s16x8 r;
  r[0]=(short)f2b(a.x); r[1]=(short)f2b(a.y); r[2]=(short)f2b(a.z); r[3]=(short)f2b(a.w);
  r[4]=(short)f2b(c.x); r[5]=(short)f2b(c.y); r[6]=(short)f2b(c.z); r[7]=(short)f2b(c.w);
  return r;
}
__device__ __forceinline__ float wsum(float v){
  #pragma unroll
  for (int o=32;o;o>>=1) v += __shfl_xor(v, o, 64);
  return v;
}

// Block-local dtype detection (deterministic).
__device__ __forceinline__ void detect_flags(const void* q, const void* mask,
                                             int& mbytes, int& bf){
  __shared__ int s_bf, s_mb;
  int t = threadIdx.x;
  if (t == 0){ s_bf = 0; s_mb = 0; }
  __syncthreads();
  if (t < 256){
    float x = fabsf(((const float*)q)[t]);
    if (x > 1e-6f && x < 100.0f) atomicAdd(&s_bf, 1);
    unsigned int mw = ((const unsigned int*)mask)[t];
    if (mw > 1u) atomicOr(&s_mb, 1);
  }
  __syncthreads();
  bf = (s_bf < 128) ? 1 : 0;
  mbytes = s_mb;
}

// ---------------- K1: fused prep (unchanged, passing) ----------------
__global__ __launch_bounds__(256) void k_prep(const void* q, const void* kk,
    const void* v, const void* sh, const void* fc, const void* mask,
    float* e, unsigned short* vtf){
  int mbytes, bf;
  detect_flags(q, mask, mbytes, bf);
  (void)mbytes;
  int lane = threadIdx.x & 63;

  if (blockIdx.x >= 1024){
    int wid = ((blockIdx.x - 1024) << 2) + (threadIdx.x >> 6);   // 0..16383
    long base = (long)wid * DD + lane * 4;
    float acc;
    if (bf){
      ushort4 kv = *(const ushort4*)((const unsigned short*)kk + base);
      ushort4 wv = *(const ushort4*)((const unsigned short*)sh + DD + lane*4);
      acc = b2f(kv.x)*b2f(wv.x) + b2f(kv.y)*b2f(wv.y)
          + b2f(kv.z)*b2f(wv.z) + b2f(kv.w)*b2f(wv.w);
    } else {
      float4 kv = *(const float4*)((const float*)kk + base);
      float4 wv = *(const float4*)((const float*)sh + DD + lane*4);
      acc = kv.x*wv.x + kv.y*wv.y + kv.z*wv.z + kv.w*wv.w;
    }
    acc = wsum(acc);
    if (lane == 0) e[wid] = __expf(acc);
    return;
  }

  // vt path: vtf[b][kk][d][8] = (fc_w @ v^T), element (b,j,d) at
  // ((b*256 + (j>>3))*256 + d)*8 + (j&7).
  int wid  = (blockIdx.x << 2) + (threadIdx.x >> 6);   // 0..4095
  int dbase = (wid & 15) << 4;
  int jbase = (wid >> 4) << 6;
  int r = lane & 15, g = lane >> 4;
  f32x4 acc[4];
  #pragma unroll
  for (int t2=0;t2<4;t2++) acc[t2] = (f32x4){0.f,0.f,0.f,0.f};
  #pragma unroll
  for (int ks = 0; ks < 8; ++ks){
    int k0 = ks*32 + g*8;
    s16x8 bv = ld8(fc, (long)(dbase + r)*DD + k0, bf);
    #pragma unroll
    for (int t2 = 0; t2 < 4; ++t2){
      s16x8 a = ld8(v, (long)(jbase + t2*16 + r)*DD + k0, bf);
      acc[t2] = __builtin_amdgcn_mfma_f32_16x16x32_bf16(a, bv, acc[t2], 0, 0, 0);
    }
  }
  int b  = jbase >> 11;
  int jj = jbase & 2047;
  int d  = dbase + r;
  #pragma unroll
  for (int t2 = 0; t2 < 4; ++t2){
    int kidx = (jj >> 3) + t2*2 + (g >> 1);
    long idx = ((long)(b*256 + kidx))*2048 + (long)d*8 + (g & 1)*4;
    ushort4 w4;
    w4.x = f2b(acc[t2][0]); w4.y = f2b(acc[t2][1]);
    w4.z = f2b(acc[t2][2]); w4.w = f2b(acc[t2][3]);
    *(ushort4*)(vtf + idx) = w4;
  }
}

// ---------------- K2: mask -> attn out + packed bits + row scales ----------------
// Round-5 proven streaming kernel (28 VGPR -> high occupancy). One wave/row.
// bits layout: bits[row*64 + l] bit (w*4+c) = mask[row][w*256 + l*4 + c].
__global__ __launch_bounds__(256) void k_mask(const void* q, const void* mask,
    const float* e, void* d_out, unsigned int* bits, float* scale){
  int mbytes, bf;
  detect_flags(q, mask, mbytes, bf);
  int row  = (blockIdx.x << 2) + (threadIdx.x >> 6);   // 0..16383
  int lane = threadIdx.x & 63;
  int b = row >> 11;
  const float* eb = e + b * LK;
  long rowm = (long)row * LK;
  unsigned int bw = 0;
  float4 ev[8];
  float s = 0.f;
  #pragma unroll
  for (int w = 0; w < 8; ++w){
    int j = (w << 8) + (lane << 2);
    unsigned int m4;
    if (mbytes){
      unsigned int mb = *(const unsigned int*)((const unsigned char*)mask + rowm + j);
      m4 = (mb & 1u) | ((mb >> 7) & 2u) | ((mb >> 14) & 4u) | ((mb >> 21) & 8u);
    } else {
      int4 mi = *(const int4*)((const int*)mask + rowm + j);
      m4 = (mi.x?1u:0u) | (mi.y?2u:0u) | (mi.z?4u:0u) | (mi.w?8u:0u);
    }
    bw |= m4 << (w*4);
    ev[w] = *(const float4*)(eb + j);
    if (!(m4 & 1u)) s += ev[w].x;
    if (!(m4 & 2u)) s += ev[w].y;
    if (!(m4 & 4u)) s += ev[w].z;
    if (!(m4 & 8u)) s += ev[w].w;
  }
  s = wsum(s);
  float scal = (s > 0.f) ? (1.0f/s) : -1.0f;
  bits[(long)row*64 + lane] = bw;
  if (lane == 0) scale[row] = scal;
  #pragma unroll
  for (int w = 0; w < 8; ++w){
    int j = (w << 8) + (lane << 2);
    float p0,p1,p2,p3;
    if (scal < 0.f){ p0=p1=p2=p3 = 1.0f/2048.0f; }
    else {
      p0 = (bw >> (w*4  )) & 1u ? 0.f : ev[w].x * scal;
      p1 = (bw >> (w*4+1)) & 1u ? 0.f : ev[w].y * scal;
      p2 = (bw >> (w*4+2)) & 1u ? 0.f : ev[w].z * scal;
      p3 = (bw >> (w*4+3)) & 1u ? 0.f : ev[w].w * scal;
    }
    if (bf){
      ushort4 u4; u4.x=f2b(p0); u4.y=f2b(p1); u4.z=f2b(p2); u4.w=f2b(p3);
      *(ushort4*)((unsigned short*)d_out + OUT0_N + rowm + j) = u4;
    } else {
      float4 f4 = {p0,p1,p2,p3};
      *(float4*)((float*)d_out + OUT0_N + rowm + j) = f4;
    }
  }
}

// A-frag: 8 bf16 p-values for (row, kk..kk+7), masked entries zeroed.
__device__ __forceinline__ s16x8 afrag(const unsigned int (*bits_s)[66],
    const unsigned short* e16_s, int row, int kk){
  int w0 = (kk >> 2) & 63;            // even
  int nib4 = (kk >> 8) << 2;
  uint2 bw2 = *(const uint2*)(&bits_s[row][w0]);   // one aligned b64
  unsigned lo = (bw2.x >> nib4) & 0xFu;
  unsigned hi = (bw2.y >> nib4) & 0xFu;
  unsigned m8 = lo | (hi << 4);
  union { s16x8 v; unsigned u[4]; } a;
  a.v = *(const s16x8*)(&e16_s[kk]);
  #pragma unroll
  for (int i = 0; i < 4; ++i){
    unsigned w = a.u[i];
    w = (m8 & (1u << (2*i)))   ? (w & 0xFFFF0000u) : w;
    w = (m8 & (1u << (2*i+1))) ? (w & 0x0000FFFFu) : w;
    a.u[i] = w;
  }
  return a.v;
}

// ---------------- K3: LDS-staged barrier-free PV GEMM + residual + LN ----------------
// Round-15 k_pvf with phase 0 replaced by bits/scale global->LDS staging (round-9
// passing pattern). BM=32 x BN=256, 512 threads = 8 waves (ks x nh).
__global__ __launch_bounds__(512, 4) void k_gemm(void* d_out, const unsigned short* vtf,
    const void* q, const void* gamp, const void* betp, const void* mask,
    const unsigned int* bits, const float* e, const float* scaleg){
  __shared__ __align__(16) char smem[80256];
  unsigned int (*bits_s)[66] = reinterpret_cast<unsigned int(*)[66]>(smem + 65536);
  unsigned short* e16_s      = (unsigned short*)(smem + 73984);
  float* scale_s             = (float*)(smem + 78080);
  float* gs                  = (float*)(smem + 78208);
  float* bs                  = (float*)(smem + 79232);
  float* redp                = (float*)smem;
  #define RED(nh_, row_, col_) redp[(((nh_)*32)+(row_))*132 + (col_)]

  int mbytes, bf;
  detect_flags(q, mask, mbytes, bf);
  (void)mbytes;
  // bijective XCD swizzle: 512 wgs -> XCD x owns batch x
  int o     = ((blockIdx.x & 7) << 6) + (blockIdx.x >> 3);
  int b     = o >> 6;
  int rbase = (o & 63) << 5;
  int t = threadIdx.x, lane = t & 63, wid = t >> 6;
  int nh = wid & 1, ks = wid >> 1;
  int r16 = lane >> 4, c16 = lane & 15;
  int dbase = nh << 7;
  const float* eb = e + b * LK;
  const unsigned short* vtfb = vtf + (long)b * 256 * 2048;
  char* stag = smem + wid * 8192;   // wave-private: 2 slots x 4096

  auto STAGE = [&](int j){
    int ss = j >> 1, h = j & 1;
    int k0 = (ks << 9) + (ss << 5);
    const char* g = (const char*)vtfb +
        (((long)((k0 >> 3) + r16) * 256 + dbase + c16) << 4);
    char* lb = stag + (j & 1) * 4096;
    #pragma unroll
    for (int i = 0; i < 4; ++i)
      __builtin_amdgcn_global_load_lds(
        (const GAS unsigned int*)(g + h*1024 + i*256),
        (LAS unsigned int*)(lb + i*1024), 16, 0, 0);
  };

  // ---- prologue prefetch ----
  STAGE(0); STAGE(1);

  // ---- staging: e16, bits, scale, LN params (round-9 passing pattern) ----
  { float4 ef = ((const float4*)eb)[t];
    ushort4 u; u.x=f2b(ef.x); u.y=f2b(ef.y); u.z=f2b(ef.z); u.w=f2b(ef.w);
    *(ushort4*)(&e16_s[t*4]) = u; }
  { int rr = t >> 4, wq = (t & 15) << 2;
    uint4 wv = *(const uint4*)(bits + ((long)(b*LQ + rbase + rr))*64 + wq);
    bits_s[rr][wq+0]=wv.x; bits_s[rr][wq+1]=wv.y;
    bits_s[rr][wq+2]=wv.z; bits_s[rr][wq+3]=wv.w; }
  if (t < 32) scale_s[t] = scaleg[(long)b*LQ + rbase + t];
  if (t < 256){ gs[t] = ldf(gamp, t, bf); bs[t] = ldf(betp, t, bf); }
  __syncthreads();

  float sc0 = scale_s[c16];
  float sc1 = scale_s[16 + c16];
  s16x8 cf;                                  // bf16(1/2048) = 0x3A00
  #pragma unroll
  for (int i = 0; i < 8; ++i) cf[i] = (short)0x3A00;

  f32x4 acc[2][8];
  #pragma unroll
  for (int i=0;i<2;i++)
    #pragma unroll
    for (int j=0;j<8;j++) acc[i][j] = (f32x4){0.f,0.f,0.f,0.f};

  // ---- main loop: identical to round 15 (passing) ----
  #pragma unroll 1
  for (int s = 0; s < 16; ++s){
    int k0 = (ks << 9) + (s << 5);
    s16x8 A0 = (sc0 < 0.f) ? cf : afrag(bits_s, e16_s, c16,      k0 + r16*8);
    s16x8 A1 = (sc1 < 0.f) ? cf : afrag(bits_s, e16_s, 16 + c16, k0 + r16*8);
    #pragma unroll
    for (int h = 0; h < 2; ++h){
      int j = 2*s + h;
      if (j < 31) asm volatile("s_waitcnt vmcnt(4)" ::: "memory");
      else        asm volatile("s_waitcnt vmcnt(0)" ::: "memory");
      const char* lb = stag + (j & 1) * 4096;
      s16x8 Bv0 = *(const s16x8*)(lb +    0 + (lane << 4));
      s16x8 Bv1 = *(const s16x8*)(lb + 1024 + (lane << 4));
      s16x8 Bv2 = *(const s16x8*)(lb + 2048 + (lane << 4));
      s16x8 Bv3 = *(const s16x8*)(lb + 3072 + (lane << 4));
      acc[0][h*4+0] = __builtin_amdgcn_mfma_f32_16x16x32_bf16(A0, Bv0, acc[0][h*4+0], 0,0,0);
      acc[1][h*4+0] = __builtin_amdgcn_mfma_f32_16x16x32_bf16(A1, Bv0, acc[1][h*4+0], 0,0,0);
      acc[0][h*4+1] = __builtin_amdgcn_mfma_f32_16x16x32_bf16(A0, Bv1, acc[0][h*4+1], 0,0,0);
      acc[1][h*4+1] = __builtin_amdgcn_mfma_f32_16x16x32_bf16(A1, Bv1, acc[1][h*4+1], 0,0,0);
      acc[0][h*4+2] = __builtin_amdgcn_mfma_f32_16x16x32_bf16(A0, Bv2, acc[0][h*4+2], 0,0,0);
      acc[1][h*4+2] = __builtin_amdgcn_mfma_f32_16x16x32_bf16(A1, Bv2, acc[1][h*4+2], 0,0,0);
      acc[0][h*4+3] = __builtin_amdgcn_mfma_f32_16x16x32_bf16(A0, Bv3, acc[0][h*4+3], 0,0,0);
      acc[1][h*4+3] = __builtin_amdgcn_mfma_f32_16x16x32_bf16(A1, Bv3, acc[1][h*4+3], 0,0,0);
      asm volatile("s_waitcnt lgkmcnt(0)" ::: "memory");
      __builtin_amdgcn_sched_barrier(0);
      if (j + 2 < 32) STAGE(j + 2);
    }
  }
  __syncthreads();   // staging region dies here; red overlays it

  // ---- reduce 4 k-slices (3 rounds into ks==0, then final dump) ----
  #pragma unroll
  for (int r = 1; r < 4; ++r){
    if (ks == r){
      #pragma unroll
      for (int mi = 0; mi < 2; ++mi)
        #pragma unroll
        for (int ni = 0; ni < 8; ++ni)
          #pragma unroll
          for (int reg = 0; reg < 4; ++reg)
            RED(nh, mi*16 + r16*4 + reg, ni*16 + c16) = acc[mi][ni][reg];
    }
    __syncthreads();
    if (ks == 0){
      #pragma unroll
      for (int mi = 0; mi < 2; ++mi)
        #pragma unroll
        for (int ni = 0; ni < 8; ++ni)
          #pragma unroll
          for (int reg = 0; reg < 4; ++reg)
            acc[mi][ni][reg] += RED(nh, mi*16 + r16*4 + reg, ni*16 + c16);
    }
    __syncthreads();
  }
  if (ks == 0){
    #pragma unroll
    for (int mi = 0; mi < 2; ++mi)
      #pragma unroll
      for (int ni = 0; ni < 8; ++ni)
        #pragma unroll
        for (int reg = 0; reg < 4; ++reg)
          RED(nh, mi*16 + r16*4 + reg, ni*16 + c16) = acc[mi][ni][reg];
  }
  __syncthreads();

  // ---- epilogue: all 512 threads; thread t -> row t>>4, cols (t&15)*16..+16 ----
  {
    int row = t >> 4, cg = t & 15;
    int nh2 = cg >> 3, coff = (cg & 7) << 4;
    float sc = scale_s[row];
    float sce = (sc < 0.f) ? 1.0f : sc;
    long grow = (long)b*LQ + rbase + row;
    float xv[16];
    float ps = 0.f, pq = 0.f;
    #pragma unroll
    for (int i4 = 0; i4 < 4; ++i4){
      float4 rv = *(const float4*)(&RED(nh2, row, coff + i4*4));
      float rr[4] = {rv.x, rv.y, rv.z, rv.w};
      int col0 = (cg << 4) + i4*4;
      float qv[4];
      if (bf){
        const unsigned short* qp = (const unsigned short*)q + grow*DD + col0;
        qv[0]=b2f(qp[0]); qv[1]=b2f(qp[1]); qv[2]=b2f(qp[2]); qv[3]=b2f(qp[3]);
      } else {
        float4 qf = *(const float4*)((const float*)q + grow*DD + col0);
        qv[0]=qf.x; qv[1]=qf.y; qv[2]=qf.z; qv[3]=qf.w;
      }
      #pragma unroll
      for (int i = 0; i < 4; ++i){
        float x = rr[i]*sce + qv[i];
        xv[i4*4 + i] = x;
        ps += x; pq += x*x;
      }
    }
    ps += __shfl_xor(ps, 1, 64); pq += __shfl_xor(pq, 1, 64);
    ps += __shfl_xor(ps, 2, 64); pq += __shfl_xor(pq, 2, 64);
    ps += __shfl_xor(ps, 4, 64); pq += __shfl_xor(pq, 4, 64);
    ps += __shfl_xor(ps, 8, 64); pq += __shfl_xor(pq, 8, 64);
    float mu = ps * (1.0f/256.0f);
    float var = pq * (1.0f/256.0f) - mu*mu;
    float rs = rsqrtf(var + 1e-5f);
    #pragma unroll
    for (int i4 = 0; i4 < 4; ++i4){
      int col0 = (cg << 4) + i4*4;
      float y[4];
      #pragma unroll
      for (int i = 0; i < 4; ++i){
        int col = col0 + i;
        y[i] = (xv[i4*4 + i] - mu) * rs * gs[col] + bs[col];
      }
      long oi = grow*(long)DD + col0;
      if (bf){
        ushort4 u4; u4.x=f2b(y[0]); u4.y=f2b(y[1]); u4.z=f2b(y[2]); u4.w=f2b(y[3]);
        *(ushort4*)((unsigned short*)d_out + oi) = u4;
      } else {
        float4 f4 = {y[0],y[1],y[2],y[3]};
        *(float4*)((float*)d_out + oi) = f4;
      }
    }
  }
  #undef RED
}

extern "C" void kernel_launch(void* const* d_in, const int* in_sizes, int n_in,
                              void* d_out, int out_size, void* d_ws, size_t ws_size,
                              hipStream_t stream) {
  const void* q    = d_in[0];
  const void* k    = d_in[1];
  const void* v    = d_in[2];
  const void* sh   = d_in[3];
  const void* fc   = d_in[4];
  const void* gam  = d_in[5];
  const void* bet  = d_in[6];
  const void* mask = d_in[7];

  float*          e     = (float*)((char*)d_ws + 65536);            // 64 KB
  float*          scale = (float*)((char*)d_ws + 131072);           // 64 KB
  unsigned int*   bits  = (unsigned int*)((char*)d_ws + 262144);    // 4 MB
  unsigned short* vtf   = (unsigned short*)((char*)d_ws + 4456448); // 8.4 MB

  k_prep<<<5120, 256, 0, stream>>>(q, k, v, sh, fc, mask, e, vtf);
  k_mask<<<4096, 256, 0, stream>>>(q, mask, e, d_out, bits, scale);
  k_gemm<<<512,  512, 0, stream>>>(d_out, vtf, q, gam, bet, mask, bits, e, scale);
}

// Round 17
// 126.578 us; speedup vs baseline: 1.1081x; 1.1081x over previous
//
#include <hip/hip_runtime.h>
#include <hip/hip_bf16.h>

// Problem constants: b=8, lq=lk=2048, d=256
#define BB 8
#define LQ 2048
#define LK 2048
#define DD 256
#define OUT0_N (BB*LQ*DD)      // LN output elements; attn follows in d_out

typedef short s16x8 __attribute__((ext_vector_type(8)));
typedef float f32x4 __attribute__((ext_vector_type(4)));

#define GAS __attribute__((address_space(1)))
#define LAS __attribute__((address_space(3)))

__device__ __forceinline__ unsigned short f2b(float x){
  unsigned int u = __float_as_uint(x);
  u += 0x7fffu + ((u >> 16) & 1u);           // RNE
  return (unsigned short)(u >> 16);
}
__device__ __forceinline__ float b2f(unsigned short h){
  return __uint_as_float(((unsigned int)h) << 16);
}
__device__ __forceinline__ float ldf(const void* p, long i, int bf){
  return bf ? b2f(((const unsigned short*)p)[i]) : ((const float*)p)[i];
}
__device__ __forceinline__ s16x8 ld8(const void* p, long i, int bf){
  if (bf) return *(const s16x8*)((const unsigned short*)p + i);
  const float* f = (const float*)p + i;
  float4 a = *(const float4*)(f);
  float4 c = *(const float4*)(f + 4);
  s16x8 r;
  r[0]=(short)f2b(a.x); r[1]=(short)f2b(a.y); r[2]=(short)f2b(a.z); r[3]=(short)f2b(a.w);
  r[4]=(short)f2b(c.x); r[5]=(short)f2b(c.y); r[6]=(short)f2b(c.z); r[7]=(short)f2b(c.w);
  return r;
}
__device__ __forceinline__ float wsum(float v){
  #pragma unroll
  for (int o=32;o;o>>=1) v += __shfl_xor(v, o, 64);
  return v;
}

// Block-local dtype detection (deterministic).
__device__ __forceinline__ void detect_flags(const void* q, const void* mask,
                                             int& mbytes, int& bf){
  __shared__ int s_bf, s_mb;
  int t = threadIdx.x;
  if (t == 0){ s_bf = 0; s_mb = 0; }
  __syncthreads();
  if (t < 256){
    float x = fabsf(((const float*)q)[t]);
    if (x > 1e-6f && x < 100.0f) atomicAdd(&s_bf, 1);
    unsigned int mw = ((const unsigned int*)mask)[t];
    if (mw > 1u) atomicOr(&s_mb, 1);
  }
  __syncthreads();
  bf = (s_bf < 128) ? 1 : 0;
  mbytes = s_mb;
}

// ---------------- K1: fused prep ----------------
__global__ __launch_bounds__(256) void k_prep(const void* q, const void* kk,
    const void* v, const void* sh, const void* fc, const void* mask,
    float* e, unsigned short* vtf){
  int mbytes, bf;
  detect_flags(q, mask, mbytes, bf);
  (void)mbytes;
  int lane = threadIdx.x & 63;

  if (blockIdx.x >= 1024){
    int wid = ((blockIdx.x - 1024) << 2) + (threadIdx.x >> 6);   // 0..16383
    long base = (long)wid * DD + lane * 4;
    float acc;
    if (bf){
      ushort4 kv = *(const ushort4*)((const unsigned short*)kk + base);
      ushort4 wv = *(const ushort4*)((const unsigned short*)sh + DD + lane*4);
      acc = b2f(kv.x)*b2f(wv.x) + b2f(kv.y)*b2f(wv.y)
          + b2f(kv.z)*b2f(wv.z) + b2f(kv.w)*b2f(wv.w);
    } else {
      float4 kv = *(const float4*)((const float*)kk + base);
      float4 wv = *(const float4*)((const float*)sh + DD + lane*4);
      acc = kv.x*wv.x + kv.y*wv.y + kv.z*wv.z + kv.w*wv.w;
    }
    acc = wsum(acc);
    if (lane == 0) e[wid] = __expf(acc);
    return;
  }

  // vt path: vtf[b][kk][d][8] = (fc_w @ v^T), element (b,j,d) at
  // ((b*256 + (j>>3))*256 + d)*8 + (j&7).
  int wid  = (blockIdx.x << 2) + (threadIdx.x >> 6);   // 0..4095
  int dbase = (wid & 15) << 4;
  int jbase = (wid >> 4) << 6;
  int r = lane & 15, g = lane >> 4;
  f32x4 acc[4];
  #pragma unroll
  for (int t2=0;t2<4;t2++) acc[t2] = (f32x4){0.f,0.f,0.f,0.f};
  #pragma unroll
  for (int ks = 0; ks < 8; ++ks){
    int k0 = ks*32 + g*8;
    s16x8 bv = ld8(fc, (long)(dbase + r)*DD + k0, bf);
    #pragma unroll
    for (int t2 = 0; t2 < 4; ++t2){
      s16x8 a = ld8(v, (long)(jbase + t2*16 + r)*DD + k0, bf);
      acc[t2] = __builtin_amdgcn_mfma_f32_16x16x32_bf16(a, bv, acc[t2], 0, 0, 0);
    }
  }
  int b  = jbase >> 11;
  int jj = jbase & 2047;
  int d  = dbase + r;
  #pragma unroll
  for (int t2 = 0; t2 < 4; ++t2){
    int kidx = (jj >> 3) + t2*2 + (g >> 1);
    long idx = ((long)(b*256 + kidx))*2048 + (long)d*8 + (g & 1)*4;
    ushort4 w4;
    w4.x = f2b(acc[t2][0]); w4.y = f2b(acc[t2][1]);
    w4.z = f2b(acc[t2][2]); w4.w = f2b(acc[t2][3]);
    *(ushort4*)(vtf + idx) = w4;
  }
}

// A-frag: 8 bf16 p-values for (row, kk..kk+7), masked entries zeroed.
__device__ __forceinline__ s16x8 afrag(const unsigned int (*bits_s)[66],
    const unsigned short* e16_s, int row, int kk){
  int w0 = (kk >> 2) & 63;            // even
  int nib4 = (kk >> 8) << 2;
  uint2 bw2 = *(const uint2*)(&bits_s[row][w0]);   // one aligned b64
  unsigned lo = (bw2.x >> nib4) & 0xFu;
  unsigned hi = (bw2.y >> nib4) & 0xFu;
  unsigned m8 = lo | (hi << 4);
  union { s16x8 v; unsigned u[4]; } a;
  a.v = *(const s16x8*)(&e16_s[kk]);
  #pragma unroll
  for (int i = 0; i < 4; ++i){
    unsigned w = a.u[i];
    w = (m8 & (1u << (2*i)))   ? (w & 0xFFFF0000u) : w;
    w = (m8 & (1u << (2*i+1))) ? (w & 0x0000FFFFu) : w;
    a.u[i] = w;
  }
  return a.v;
}

// ---------------- K2: fused phase0 + LDS-staged barrier-free PV + residual + LN ----
// BM=32 x BN=256, 512 threads = 8 waves (ks 0..3 K-slices x nh col-halves).
__global__ __launch_bounds__(512, 4) void k_pvf(void* d_out, const unsigned short* vtf,
    const void* q, const void* gamp, const void* betp, const void* mask,
    const float* e){
  // LDS layout: [0,65536) wave staging (8 waves x 2 slots x 4096 B);
  //             reused as red[2][32][132] f32 after the main loop.
  __shared__ __align__(16) char smem[80256];
  unsigned int (*bits_s)[66] = reinterpret_cast<unsigned int(*)[66]>(smem + 65536);
  unsigned short* e16_s      = (unsigned short*)(smem + 73984);
  float* scale_s             = (float*)(smem + 78080);
  float* gs                  = (float*)(smem + 78208);
  float* bs                  = (float*)(smem + 79232);
  float* redp                = (float*)smem;
  #define RED(nh_, row_, col_) redp[(((nh_)*32)+(row_))*132 + (col_)]

  int mbytes, bf;
  detect_flags(q, mask, mbytes, bf);
  // bijective XCD swizzle: 512 wgs -> XCD x owns batch x
  int o     = ((blockIdx.x & 7) << 6) + (blockIdx.x >> 3);
  int b     = o >> 6;
  int rbase = (o & 63) << 5;
  int t = threadIdx.x, lane = t & 63, wid = t >> 6;
  int nh = wid & 1, ks = wid >> 1;
  int r16 = lane >> 4, c16 = lane & 15;
  int dbase = nh << 7;
  const float* eb = e + b * LK;
  const unsigned short* vtfb = vtf + (long)b * 256 * 2048;
  char* stag = smem + wid * 8192;   // wave-private: 2 slots x 4096

  auto STAGE = [&](int j){
    int ss = j >> 1, h = j & 1;
    int k0 = (ks << 9) + (ss << 5);
    const char* g = (const char*)vtfb +
        (((long)((k0 >> 3) + r16) * 256 + dbase + c16) << 4);
    char* lb = stag + (j & 1) * 4096;
    #pragma unroll
    for (int i = 0; i < 4; ++i)
      __builtin_amdgcn_global_load_lds(
        (const GAS unsigned int*)(g + h*1024 + i*256),
        (LAS unsigned int*)(lb + i*1024), 16, 0, 0);
  };

  // ---- staging: e16 + LN params ----
  { float4 ef = ((const float4*)eb)[t];
    ushort4 u; u.x=f2b(ef.x); u.y=f2b(ef.y); u.z=f2b(ef.z); u.w=f2b(ef.w);
    *(ushort4*)(&e16_s[t*4]) = u; }
  if (t < 256){ gs[t] = ldf(gamp, t, bf); bs[t] = ldf(betp, t, bf); }

  // ---- phase 0: mask->bits(LDS) + row scales + attn write (MLP-hoisted) ----
  unsigned short* attn16 = (unsigned short*)d_out + OUT0_N;
  float*          attn32 = (float*)d_out + OUT0_N;
  {
    float4 ev[8];
    #pragma unroll
    for (int w = 0; w < 8; ++w)
      ev[w] = *(const float4*)(eb + (w << 8) + (lane << 2));
    unsigned int mw[4][8];
    long rowm0 = ((long)(b*LQ + rbase + (wid << 2))) * (long)LK;
    if (mbytes){
      #pragma unroll
      for (int rr = 0; rr < 4; ++rr)
        #pragma unroll
        for (int w = 0; w < 8; ++w)
          mw[rr][w] = *(const unsigned int*)((const unsigned char*)mask
                        + rowm0 + (long)rr*LK + (w << 8) + (lane << 2));
      #pragma unroll
      for (int rr = 0; rr < 4; ++rr)
        #pragma unroll
        for (int w = 0; w < 8; ++w){
          unsigned int mb = mw[rr][w];
          mw[rr][w] = (mb & 1u) | ((mb >> 7) & 2u) | ((mb >> 14) & 4u) | ((mb >> 21) & 8u);
        }
    } else {
      #pragma unroll
      for (int rr = 0; rr < 4; ++rr)
        #pragma unroll
        for (int w = 0; w < 8; ++w){
          int4 mi = *(const int4*)((const int*)mask + rowm0 + (long)rr*LK
                        + (w << 8) + (lane << 2));
          mw[rr][w] = (mi.x?1u:0u) | (mi.y?2u:0u) | (mi.z?4u:0u) | (mi.w?8u:0u);
        }
    }
    #pragma unroll
    for (int rr = 0; rr < 4; ++rr){
      int row = (wid << 2) + rr;
      long rowm = rowm0 + (long)rr*LK;
      unsigned int bw = 0;
      float s = 0.f;
      #pragma unroll
      for (int w = 0; w < 8; ++w){
        unsigned int m4 = mw[rr][w];
        bw |= m4 << (w*4);
        if (!(m4 & 1u)) s += ev[w].x;
        if (!(m4 & 2u)) s += ev[w].y;
        if (!(m4 & 4u)) s += ev[w].z;
        if (!(m4 & 8u)) s += ev[w].w;
      }
      s = wsum(s);
      float scal = (s > 0.f) ? (1.0f/s) : -1.0f;
      bits_s[row][lane] = bw;
      if (lane == 0) scale_s[row] = scal;
      #pragma unroll
      for (int w = 0; w < 8; ++w){
        unsigned int m4 = mw[rr][w];
        float p0,p1,p2,p3;
        if (scal < 0.f){ p0=p1=p2=p3 = 1.0f/2048.0f; }
        else {
          p0 = (m4 & 1u) ? 0.f : ev[w].x * scal;
          p1 = (m4 & 2u) ? 0.f : ev[w].y * scal;
          p2 = (m4 & 4u) ? 0.f : ev[w].z * scal;
          p3 = (m4 & 8u) ? 0.f : ev[w].w * scal;
        }
        int j = (w << 8) + (lane << 2);
        if (bf){
          ushort4 u4; u4.x=f2b(p0); u4.y=f2b(p1); u4.z=f2b(p2); u4.w=f2b(p3);
          *(ushort4*)(attn16 + rowm + j) = u4;
        } else {
          float4 f4 = {p0,p1,p2,p3};
          *(float4*)(attn32 + rowm + j) = f4;
        }
      }
    }
  }
  // prologue prefetch: lands during the barrier drain
  STAGE(0); STAGE(1);
  __syncthreads();

  float sc0 = scale_s[c16];
  float sc1 = scale_s[16 + c16];
  s16x8 cf;                                  // bf16(1/2048) = 0x3A00
  #pragma unroll
  for (int i = 0; i < 8; ++i) cf[i] = (short)0x3A00;

  f32x4 acc[2][8];
  #pragma unroll
  for (int i=0;i<2;i++)
    #pragma unroll
    for (int j=0;j<8;j++) acc[i][j] = (f32x4){0.f,0.f,0.f,0.f};

  // ---- main loop: 16 k-steps x 2 halves, counted vmcnt; race-free:
  //      STAGE(j+2) (same slot) issues only after lgkmcnt(0) proves the
  //      slot's ds_reads landed in VGPRs. ----
  #pragma unroll 1
  for (int s = 0; s < 16; ++s){
    int k0 = (ks << 9) + (s << 5);
    s16x8 A0 = (sc0 < 0.f) ? cf : afrag(bits_s, e16_s, c16,      k0 + r16*8);
    s16x8 A1 = (sc1 < 0.f) ? cf : afrag(bits_s, e16_s, 16 + c16, k0 + r16*8);
    #pragma unroll
    for (int h = 0; h < 2; ++h){
      int j = 2*s + h;
      if (j < 31) asm volatile("s_waitcnt vmcnt(4)" ::: "memory");
      else        asm volatile("s_waitcnt vmcnt(0)" ::: "memory");
      const char* lb = stag + (j & 1) * 4096;
      s16x8 Bv0 = *(const s16x8*)(lb +    0 + (lane << 4));
      s16x8 Bv1 = *(const s16x8*)(lb + 1024 + (lane << 4));
      s16x8 Bv2 = *(const s16x8*)(lb + 2048 + (lane << 4));
      s16x8 Bv3 = *(const s16x8*)(lb + 3072 + (lane << 4));
      asm volatile("s_waitcnt lgkmcnt(0)" ::: "memory");
      __builtin_amdgcn_sched_barrier(0);
      if (j + 2 < 32) STAGE(j + 2);
      acc[0][h*4+0] = __builtin_amdgcn_mfma_f32_16x16x32_bf16(A0, Bv0, acc[0][h*4+0], 0,0,0);
      acc[1][h*4+0] = __builtin_amdgcn_mfma_f32_16x16x32_bf16(A1, Bv0, acc[1][h*4+0], 0,0,0);
      acc[0][h*4+1] = __builtin_amdgcn_mfma_f32_16x16x32_bf16(A0, Bv1, acc[0][h*4+1], 0,0,0);
      acc[1][h*4+1] = __builtin_amdgcn_mfma_f32_16x16x32_bf16(A1, Bv1, acc[1][h*4+1], 0,0,0);
      acc[0][h*4+2] = __builtin_amdgcn_mfma_f32_16x16x32_bf16(A0, Bv2, acc[0][h*4+2], 0,0,0);
      acc[1][h*4+2] = __builtin_amdgcn_mfma_f32_16x16x32_bf16(A1, Bv2, acc[1][h*4+2], 0,0,0);
      acc[0][h*4+3] = __builtin_amdgcn_mfma_f32_16x16x32_bf16(A0, Bv3, acc[0][h*4+3], 0,0,0);
      acc[1][h*4+3] = __builtin_amdgcn_mfma_f32_16x16x32_bf16(A1, Bv3, acc[1][h*4+3], 0,0,0);
    }
  }
  __syncthreads();   // staging region dies here; red overlays it

  // ---- reduce 4 k-slices (3 rounds into ks==0, then final dump) ----
  #pragma unroll
  for (int r = 1; r < 4; ++r){
    if (ks == r){
      #pragma unroll
      for (int mi = 0; mi < 2; ++mi)
        #pragma unroll
        for (int ni = 0; ni < 8; ++ni)
          #pragma unroll
          for (int reg = 0; reg < 4; ++reg)
            RED(nh, mi*16 + r16*4 + reg, ni*16 + c16) = acc[mi][ni][reg];
    }
    __syncthreads();
    if (ks == 0){
      #pragma unroll
      for (int mi = 0; mi < 2; ++mi)
        #pragma unroll
        for (int ni = 0; ni < 8; ++ni)
          #pragma unroll
          for (int reg = 0; reg < 4; ++reg)
            acc[mi][ni][reg] += RED(nh, mi*16 + r16*4 + reg, ni*16 + c16);
    }
    __syncthreads();
  }
  if (ks == 0){
    #pragma unroll
    for (int mi = 0; mi < 2; ++mi)
      #pragma unroll
      for (int ni = 0; ni < 8; ++ni)
        #pragma unroll
        for (int reg = 0; reg < 4; ++reg)
          RED(nh, mi*16 + r16*4 + reg, ni*16 + c16) = acc[mi][ni][reg];
  }
  __syncthreads();

  // ---- epilogue: all 512 threads; thread t -> row t>>4, cols (t&15)*16..+16 ----
  {
    int row = t >> 4, cg = t & 15;
    int nh2 = cg >> 3, coff = (cg & 7) << 4;
    float sc = scale_s[row];
    float sce = (sc < 0.f) ? 1.0f : sc;
    long grow = (long)b*LQ + rbase + row;
    float xv[16];
    float ps = 0.f, pq = 0.f;
    #pragma unroll
    for (int i4 = 0; i4 < 4; ++i4){
      float4 rv = *(const float4*)(&RED(nh2, row, coff + i4*4));
      float rr[4] = {rv.x, rv.y, rv.z, rv.w};
      int col0 = (cg << 4) + i4*4;
      float qv[4];
      if (bf){
        const unsigned short* qp = (const unsigned short*)q + grow*DD + col0;
        qv[0]=b2f(qp[0]); qv[1]=b2f(qp[1]); qv[2]=b2f(qp[2]); qv[3]=b2f(qp[3]);
      } else {
        float4 qf = *(const float4*)((const float*)q + grow*DD + col0);
        qv[0]=qf.x; qv[1]=qf.y; qv[2]=qf.z; qv[3]=qf.w;
      }
      #pragma unroll
      for (int i = 0; i < 4; ++i){
        float x = rr[i]*sce + qv[i];
        xv[i4*4 + i] = x;
        ps += x; pq += x*x;
      }
    }
    ps += __shfl_xor(ps, 1, 64); pq += __shfl_xor(pq, 1, 64);
    ps += __shfl_xor(ps, 2, 64); pq += __shfl_xor(pq, 2, 64);
    ps += __shfl_xor(ps, 4, 64); pq += __shfl_xor(pq, 4, 64);
    ps += __shfl_xor(ps, 8, 64); pq += __shfl_xor(pq, 8, 64);
    float mu = ps * (1.0f/256.0f);
    float var = pq * (1.0f/256.0f) - mu*mu;
    float rs = rsqrtf(var + 1e-5f);
    #pragma unroll
    for (int i4 = 0; i4 < 4; ++i4){
      int col0 = (cg << 4) + i4*4;
      float y[4];
      #pragma unroll
      for (int i = 0; i < 4; ++i){
        int col = col0 + i;
        y[i] = (xv[i4*4 + i] - mu) * rs * gs[col] + bs[col];
      }
      long oi = grow*(long)DD + col0;
      if (bf){
        ushort4 u4; u4.x=f2b(y[0]); u4.y=f2b(y[1]); u4.z=f2b(y[2]); u4.w=f2b(y[3]);
        *(ushort4*)((unsigned short*)d_out + oi) = u4;
      } else {
        float4 f4 = {y[0],y[1],y[2],y[3]};
        *(float4*)((float*)d_out + oi) = f4;
      }
    }
  }
  #undef RED
}

extern "C" void kernel_launch(void* const* d_in, const int* in_sizes, int n_in,
                              void* d_out, int out_size, void* d_ws, size_t ws_size,
                              hipStream_t stream) {
  const void* q    = d_in[0];
  const void* k    = d_in[1];
  const void* v    = d_in[2];
  const void* sh   = d_in[3];
  const void* fc   = d_in[4];
  const void* gam  = d_in[5];
  const void* bet  = d_in[6];
  const void* mask = d_in[7];

  float*          e   = (float*)((char*)d_ws + 65536);            // 64 KB
  unsigned short* vtf = (unsigned short*)((char*)d_ws + 4456448); // 8.4 MB

  k_prep<<<5120, 256, 0, stream>>>(q, k, v, sh, fc, mask, e, vtf);
  k_pvf <<<512,  512, 0, stream>>>(d_out, vtf, q, gam, bet, mask, e);
}